// Round 4
// baseline (508.958 us; speedup 1.0000x reference)
//
#include <hip/hip_runtime.h>
#include <hip/hip_bf16.h>

// DTM decoder, fp32 in/out. Round-8 structure ("A stays out of LDS"):
//   K0 prep_pack   : temb fp32 -> A_hi/A_lo bf16 PACKED in MFMA-fragment
//                    order [g=k/8][row][8] (rows 500..511 zero); zero rsum.
//   K1 gemm_logits : BM=512 (all rows, one m-pass -> W cvt'd ONCE), BN=64,
//                    8 waves x (64x64). A-frags loaded DIRECT from L2-resident
//                    packed arrays (coalesced 16B/lane); LDS holds only the
//                    64x64 W hi/lo tile (16KB). W fp32 reg-prefetch(t+1) under
//                    MFMA; raw s_barrier + lgkmcnt(0) only (W loads in flight
//                    across barriers). 3-term split (Ah@Bh + Ah@Bl + Al@Bh).
//                    Epilogue: P-hat=exp(l-180), rowsum atomics, P-hat^T bf16
//                    (each block writes FULL 512-k rows for its 64 vocab).
//   K3 build_theta2: T2 packed [g][i][8] = theta[i,r-50t]/rowsum (else 0).
//   K4 gemm_out    : stage FULL Pt block (64x512=64KB) once via GLDS burst,
//                    then barrier-free K-loop: A direct from packed T2 (L2),
//                    B from chunk-swizzled LDS. out(256,50000) fp32.
// ws: Pt(50048x512 bf16) | rsum 2KB | Ahp 1MB | Alp 1MB ; T2p aliases Ahp.

typedef __bf16 bf16_t;
typedef __bf16 bf16x4 __attribute__((ext_vector_type(4)));
typedef __bf16 bf16x8 __attribute__((ext_vector_type(8)));
typedef float f32x4 __attribute__((ext_vector_type(4)));

typedef __attribute__((address_space(1))) void gvoid;
typedef __attribute__((address_space(3))) void svoid;
#define GLDS(SRC, DST) \
    __builtin_amdgcn_global_load_lds((gvoid*)(SRC), (svoid*)(DST), 16, 0, 0)
#define MFMA16(A, B, C) __builtin_amdgcn_mfma_f32_16x16x32_bf16((A), (B), (C), 0, 0, 0)

#define SHIFT 180.0f
#define TTS2 72  // per-wave transpose stride (64 k + 8 pad, 16B-aligned rows)

__device__ __forceinline__ void cvt8(float4 a, float4 b, bf16x8& h, bf16x8& l)
{
    float f[8] = {a.x, a.y, a.z, a.w, b.x, b.y, b.z, b.w};
#pragma unroll
    for (int j = 0; j < 8; ++j) {
        bf16_t hh = (bf16_t)f[j];
        h[j] = hh;
        l[j] = (bf16_t)(f[j] - (float)hh);
    }
}

// ---------------- K0: pack A fp32 -> (hi,lo) bf16 fragment-order ----------
// layout: [g 0..127][row 0..511][8 elems], elem addr = g*4096 + row*8 + j
__global__ void prep_pack(const float* __restrict__ x, bf16_t* __restrict__ hi,
                          bf16_t* __restrict__ lo, float* __restrict__ rsum)
{
    const int j = blockIdx.x * 256 + threadIdx.x;   // 0..65535
    if (j < 512) rsum[j] = 0.f;
    const int r = j >> 7, g = j & 127;
    float4 v0 = {0.f, 0.f, 0.f, 0.f}, v1 = v0;
    if (r < 500) {
        v0 = *(const float4*)(x + r * 1024 + g * 8);
        v1 = *(const float4*)(x + r * 1024 + g * 8 + 4);
    }
    bf16x8 h, l;
    cvt8(v0, v1, h, l);
    *(bf16x8*)(hi + g * 4096 + r * 8) = h;
    *(bf16x8*)(lo + g * 4096 + r * 8) = l;
}

// ---------------- K1: BM=512 BN=64, A direct-from-L2, B-only LDS ----------
__global__ __launch_bounds__(512, 4)
void gemm_logits(const bf16_t* __restrict__ Ahp, const bf16_t* __restrict__ Alp,
                 const float* __restrict__ W, bf16_t* __restrict__ Pt,
                 float* __restrict__ Rsum)
{
    // BsH[4096] BsL[4096] during loop; 8 x 4608 transpose area in epilogue
    __shared__ __align__(16) bf16_t sm[36864];      // 73,728 B -> 2 blocks/CU
    bf16_t* BsH = sm;
    bf16_t* BsL = sm + 4096;

    const int tid = threadIdx.x;
    const int wv = tid >> 6, lane = tid & 63;       // 8 waves, wave wv owns
    const int bn0 = blockIdx.x * 64;                //   m-rows wv*64..+63
    const int lrow = lane & 15, q = lane >> 4;

    // W staging: thread -> (row = tid>>3, 8-float chunk kch = tid&7)
    const int wrow_l = tid >> 3;                    // 0..63
    int wrow_g = bn0 + wrow_l; if (wrow_g > 49999) wrow_g = 49999;
    const int kch = tid & 7;
    const float4* wp0 = (const float4*)(W + (long)wrow_g * 1024) + kch * 2;
    const int sob = wrow_l * 64 + ((kch ^ (wrow_l & 7)) * 8);

    const int arow = wv * 64 + lrow;

    f32x4 acc[4][4] = {};
    float4 wc0 = wp0[0], wc1 = wp0[1];
    float4 wn0, wn1;

    for (int t = 0; t < 16; ++t) {
        if (t < 15) { wn0 = wp0[(t + 1) * 16]; wn1 = wp0[(t + 1) * 16 + 1]; }
        // A prefetch kk=0 (global/L2, independent of the barrier)
        bf16x8 ah0[4], al0[4];
        {
            const int g = t * 8 + q;
#pragma unroll
            for (int a = 0; a < 4; ++a) {
                const int ro = g * 4096 + (arow + a * 16) * 8;
                ah0[a] = *(const bf16x8*)(Ahp + ro);
                al0[a] = *(const bf16x8*)(Alp + ro);
            }
        }
        // stage W(t): fp32 regs -> hi/lo -> swizzled LDS
        {
            bf16x8 h, l;
            cvt8(wc0, wc1, h, l);
            *(bf16x8*)(BsH + sob) = h;
            *(bf16x8*)(BsL + sob) = l;
        }
        asm volatile("s_waitcnt lgkmcnt(0)" ::: "memory");
        __builtin_amdgcn_s_barrier();               // no vmcnt drain: W(t+1)
                                                    // and A-frags keep flying
        // ---- kk = 0 ----
        {
            const int kg = q;
#pragma unroll
            for (int b = 0; b < 4; ++b) {
                const int n = b * 16 + lrow;
                const int off = n * 64 + ((kg ^ (n & 7)) * 8);
                bf16x8 bh = *(const bf16x8*)(BsH + off);
                bf16x8 bl = *(const bf16x8*)(BsL + off);
                __builtin_amdgcn_s_setprio(1);
#pragma unroll
                for (int a = 0; a < 4; ++a) {
                    acc[a][b] = MFMA16(ah0[a], bh, acc[a][b]);
                    acc[a][b] = MFMA16(ah0[a], bl, acc[a][b]);
                    acc[a][b] = MFMA16(al0[a], bh, acc[a][b]);
                }
                __builtin_amdgcn_s_setprio(0);
            }
        }
        // ---- kk = 1 ----
        {
            const int g = t * 8 + 4 + q;
            bf16x8 ah[4], al[4];
#pragma unroll
            for (int a = 0; a < 4; ++a) {
                const int ro = g * 4096 + (arow + a * 16) * 8;
                ah[a] = *(const bf16x8*)(Ahp + ro);
                al[a] = *(const bf16x8*)(Alp + ro);
            }
            const int kg = 4 + q;
#pragma unroll
            for (int b = 0; b < 4; ++b) {
                const int n = b * 16 + lrow;
                const int off = n * 64 + ((kg ^ (n & 7)) * 8);
                bf16x8 bh = *(const bf16x8*)(BsH + off);
                bf16x8 bl = *(const bf16x8*)(BsL + off);
                __builtin_amdgcn_s_setprio(1);
#pragma unroll
                for (int a = 0; a < 4; ++a) {
                    acc[a][b] = MFMA16(ah[a], bh, acc[a][b]);
                    acc[a][b] = MFMA16(ah[a], bl, acc[a][b]);
                    acc[a][b] = MFMA16(al[a], bh, acc[a][b]);
                }
                __builtin_amdgcn_s_setprio(0);
            }
        }
        asm volatile("s_waitcnt lgkmcnt(0)" ::: "memory");
        __builtin_amdgcn_s_barrier();               // B consumed -> reusable
        wc0 = wn0; wc1 = wn1;
    }

    // ---- epilogue: exp, rowsum atomics, P-hat^T store ----
    // wave wv owns logit rows [wv*64, +64) x vocab cols [bn0, +64)
#pragma unroll
    for (int a = 0; a < 4; ++a) {
        float rs[4] = {0.f, 0.f, 0.f, 0.f};
#pragma unroll
        for (int b = 0; b < 4; ++b) {
            const bool cok = (bn0 + b * 16 + lrow) < 50000;
#pragma unroll
            for (int r = 0; r < 4; ++r) {
                const float e = __expf(acc[a][b][r] - SHIFT);
                acc[a][b][r] = e;
                if (cok) rs[r] += e;
            }
        }
#pragma unroll
        for (int r = 0; r < 4; ++r) {
            float v = rs[r];
            v += __shfl_xor(v, 1, 16);
            v += __shfl_xor(v, 2, 16);
            v += __shfl_xor(v, 4, 16);
            v += __shfl_xor(v, 8, 16);
            const int row = wv * 64 + a * 16 + q * 4 + r;
            if (lrow == 0 && row < 500) atomicAdd(Rsum + row, v);
        }
    }
    // per-wave transpose (sm reuse is safe: all waves passed final barrier)
    bf16_t* Tt = sm + wv * (64 * TTS2);
#pragma unroll
    for (int a = 0; a < 4; ++a)
#pragma unroll
        for (int b = 0; b < 4; ++b) {
            bf16x4 p;
#pragma unroll
            for (int r = 0; r < 4; ++r) p[r] = (bf16_t)acc[a][b][r];
            *(bf16x4*)(Tt + (b * 16 + lrow) * TTS2 + a * 16 + q * 4) = p;
        }
    // coalesced store: 8 lanes cover one v-row's 128B (64 k-elems)
    const long kbase = wv * 64;
#pragma unroll
    for (int it = 0; it < 8; ++it) {
        const int u = it * 64 + lane;
        const int vl = u >> 3, ck = u & 7;
        bf16x8 d = *(const bf16x8*)(Tt + vl * TTS2 + ck * 8);
        *(bf16x8*)(Pt + (long)(bn0 + vl) * 512 + kbase + ck * 8) = d;
    }
}

// ---------------- K3: packed T2p[g][i][8] = theta/rowsum (else 0) ---------
__global__ void build_theta2(const float* __restrict__ theta,
                             const int* __restrict__ tidx,
                             const float* __restrict__ rsum,
                             bf16_t* __restrict__ T2p)
{
    const int i = blockIdx.x, rr = threadIdx.x;     // i batch, rr in [0,512)
    const int base = tidx[i] * 50;
    bf16_t v = (bf16_t)0.0f;
    if (rr >= base && rr < base + 50)
        v = (bf16_t)(theta[i * 50 + (rr - base)] / rsum[rr]);
    T2p[(rr >> 3) * 2048 + i * 8 + (rr & 7)] = v;
}

// ---------------- K4: stage full Pt-block once, barrier-free K-loop -------
__global__ __launch_bounds__(256, 4)
void gemm_out(const bf16_t* __restrict__ T2p, const bf16_t* __restrict__ Pt,
              float* __restrict__ out)
{
    __shared__ __align__(16) bf16_t Bs[32768];      // 64 KB: [64][512] swz
    const int tid = threadIdx.x;
    const int wave = tid >> 6, lane = tid & 63;
    const int bn0 = blockIdx.x * 64;
    const int lrow = lane & 15, q = lane >> 4;

    // stage all of B (this block's 64 Pt rows x 512 k) in one GLDS burst.
    // LDS dest linear (wave-uniform base), source inverse-swizzled (rule 21).
#pragma unroll
    for (int rr = 0; rr < 16; ++rr) {
        const int ub = rr * 4096 + wave * 1024;     // uniform byte base
        const int off = ub + lane * 16;             // this lane's dest byte
        const int row = off >> 10;                  // 0..63
        const int c = (off >> 4) & 63;              // 16B chunk in row
        const int cs = c ^ (row & 7);
        GLDS(Pt + (long)(bn0 + row) * 512 + cs * 8, ((char*)Bs) + ub);
    }
    __syncthreads();

    f32x4 acc[4][4] = {};
#pragma unroll 4
    for (int kk = 0; kk < 16; ++kk) {
        const int g = kk * 4 + q;                   // k-chunk 0..63
        bf16x8 af[4];
#pragma unroll
        for (int a = 0; a < 4; ++a)
            af[a] = *(const bf16x8*)(T2p + g * 2048 +
                                     (wave * 64 + a * 16 + lrow) * 8);
#pragma unroll
        for (int b = 0; b < 4; ++b) {
            const int n = b * 16 + lrow;
            bf16x8 bfr = *(const bf16x8*)(Bs + n * 512 + ((g ^ (n & 7)) * 8));
#pragma unroll
            for (int a = 0; a < 4; ++a)
                acc[a][b] = MFMA16(af[a], bfr, acc[a][b]);
        }
    }
#pragma unroll
    for (int a = 0; a < 4; ++a) {
        const int row0 = wave * 64 + a * 16 + q * 4;
#pragma unroll
        for (int b = 0; b < 4; ++b) {
            const int col = bn0 + b * 16 + lrow;
            if (col < 50000) {
#pragma unroll
                for (int r = 0; r < 4; ++r)
                    out[(long)(row0 + r) * 50000 + col] = acc[a][b][r];
            }
        }
    }
}

extern "C" void kernel_launch(void* const* d_in, const int* in_sizes, int n_in,
                              void* d_out, int out_size, void* d_ws, size_t ws_size,
                              hipStream_t stream)
{
    const float* theta = (const float*)d_in[0];   // (256,50) fp32
    const float* wemb  = (const float*)d_in[1];   // (50000,1024) fp32
    const float* temb  = (const float*)d_in[2];   // (500,1024) fp32
    const int*   tidx  = (const int*)d_in[3];     // (256,)
    float* out = (float*)d_out;                   // (256,50000) fp32

    char* ws = (char*)d_ws;
    bf16_t* Pt   = (bf16_t*)ws;                   // 50048*512*2 = 51,249,152
    float*  rsum = (float*)(ws + 51249152);       // 2 KB
    bf16_t* Ahp  = (bf16_t*)(ws + 51251200);      // 1,048,576 (packed hi)
    bf16_t* Alp  = (bf16_t*)(ws + 52299776);      // 1,048,576 (packed lo)
    bf16_t* T2p  = (bf16_t*)(ws + 51251200);      // aliases Ahp (dead post-K1)

    prep_pack   <<<dim3(256), 256, 0, stream>>>(temb, Ahp, Alp, rsum);
    gemm_logits <<<dim3(782), 512, 0, stream>>>(Ahp, Alp, wemb, Pt, rsum);
    build_theta2<<<dim3(256), 512, 0, stream>>>(theta, tidx, rsum, T2p);
    gemm_out    <<<dim3(782), 256, 0, stream>>>(T2p, Pt, out);
}

// Round 5
// 427.980 us; speedup vs baseline: 1.1892x; 1.1892x over previous
//
#include <hip/hip_runtime.h>
#include <hip/hip_bf16.h>

// DTM decoder, fp32 in/out. Round-9 structure:
//   K0 prep_pack   : temb fp32 -> A_hi/A_lo bf16 PACKED in MFMA-fragment
//                    order [g=k/8][row 0..511][8] (rows 500+ zero); zero rsum.
//   K1 gemm_logits : BM=128 BN=64, 256 thr (4 waves x 32m), A-frags DIRECT
//                    from L2-resident packed arrays (no A in LDS!); LDS holds
//                    only the 64x64 W hi/lo tile (16KB; 20.5KB block total)
//                    -> ~4 independent 4-wave groups/CU interleave stalls.
//                    Raw s_barrier + lgkmcnt(0) (W-prefetch & A-loads fly
//                    across). 3-term split (Ah@Bh+Ah@Bl+Al@Bh). setprio.
//                    XCD-chunked swizzle (3128=8*391, m-fastest within XCD).
//                    Epilogue: P-hat=exp(l-180), rowsum atomics, P-hat^T bf16.
//   K3 build_theta2: T2p packed [g][i][8] = theta[i,r-50t]/rowsum (else 0).
//   K4 gemm_out    : stage full Pt-block (64x512) once via GLDS, barrier-free
//                    MFMA loop (A direct from packed T2p), epilogue via LDS
//                    transpose -> 256B-contiguous out stores.
// ws: Pt(50048x512 bf16) | rsum 2KB | Ahp 1MB | Alp 1MB ; T2p aliases Ahp.

typedef __bf16 bf16_t;
typedef __bf16 bf16x4 __attribute__((ext_vector_type(4)));
typedef __bf16 bf16x8 __attribute__((ext_vector_type(8)));
typedef float f32x4 __attribute__((ext_vector_type(4)));

typedef __attribute__((address_space(1))) void gvoid;
typedef __attribute__((address_space(3))) void svoid;
#define GLDS(SRC, DST) \
    __builtin_amdgcn_global_load_lds((gvoid*)(SRC), (svoid*)(DST), 16, 0, 0)
#define MFMA16(A, B, C) __builtin_amdgcn_mfma_f32_16x16x32_bf16((A), (B), (C), 0, 0, 0)

#define SHIFT 180.0f
#define TTS 40  // per-wave transpose stride (32 k + 8 pad, 16B-aligned rows)

__device__ __forceinline__ void cvt8(float4 a, float4 b, bf16x8& h, bf16x8& l)
{
    float f[8] = {a.x, a.y, a.z, a.w, b.x, b.y, b.z, b.w};
#pragma unroll
    for (int j = 0; j < 8; ++j) {
        bf16_t hh = (bf16_t)f[j];
        h[j] = hh;
        l[j] = (bf16_t)(f[j] - (float)hh);
    }
}

// ---------------- K0: pack A fp32 -> (hi,lo) bf16 fragment-order ----------
// layout: [g 0..127][row 0..511][8 elems], elem addr = g*4096 + row*8 + j
__global__ void prep_pack(const float* __restrict__ x, bf16_t* __restrict__ hi,
                          bf16_t* __restrict__ lo, float* __restrict__ rsum)
{
    const int j = blockIdx.x * 256 + threadIdx.x;   // 0..65535
    if (j < 512) rsum[j] = 0.f;
    const int r = j >> 7, g = j & 127;
    float4 v0 = {0.f, 0.f, 0.f, 0.f}, v1 = v0;
    if (r < 500) {
        v0 = *(const float4*)(x + r * 1024 + g * 8);
        v1 = *(const float4*)(x + r * 1024 + g * 8 + 4);
    }
    bf16x8 h, l;
    cvt8(v0, v1, h, l);
    *(bf16x8*)(hi + g * 4096 + r * 8) = h;
    *(bf16x8*)(lo + g * 4096 + r * 8) = l;
}

// ---------------- K1: BM=128 BN=64, A direct-from-L2, B-only LDS ----------
// grid: 3128 = 4 mtiles x 782 ntiles, XCD-chunked (3128 % 8 == 0).
__global__ __launch_bounds__(256, 4)
void gemm_logits(const bf16_t* __restrict__ Ahp, const bf16_t* __restrict__ Alp,
                 const float* __restrict__ W, bf16_t* __restrict__ Pt,
                 float* __restrict__ Rsum)
{
    // loop: BsH 8KB | BsL 8KB; epilogue: 4 waves x 5120B transpose. 20.5KB.
    __shared__ __align__(16) bf16_t sm[10240];
    bf16_t* BsH = sm;                               // 4096 bf16
    bf16_t* BsL = sm + 4096;

    const int tid = threadIdx.x;
    const int wv = tid >> 6, lane = tid & 63;

    // XCD-chunked swizzle: xcd gets contiguous nid range, m varies fastest
    const int lin = blockIdx.x;
    const int nid = (lin & 7) * 391 + (lin >> 3);
    const int bm0 = (nid & 3) * 128;
    const int bn0 = (nid >> 2) * 64;

    const int lrow = lane & 15, q = lane >> 4;

    // W staging: 4 threads/row, 64 rows, 16 consecutive floats each
    const int wrow_l = tid >> 2;                    // 0..63
    int wrow_g = bn0 + wrow_l; if (wrow_g > 49999) wrow_g = 49999;
    const int kq = tid & 3;
    const float4* wp = (const float4*)(W + (long)wrow_g * 1024 + kq * 16);
    const int kga = kq * 2;
    const int so_a = wrow_l * 64 + ((kga ^ (wrow_l & 7)) * 8);
    const int so_b = wrow_l * 64 + (((kga + 1) ^ (wrow_l & 7)) * 8);

    const int arow = bm0 + wv * 32 + lrow;          // this lane's A row base

    f32x4 acc[2][4] = {};
    float4 wcur[4], wnxt[4];
#pragma unroll
    for (int j = 0; j < 4; ++j) wcur[j] = wp[j];    // t=0 preload

    for (int t = 0; t < 16; ++t) {
        // (1) A-frag loads for this t (L2-resident packed; latency covered
        //     by the cvt phase + barrier; no LDS involved)
        bf16x8 ah0[2], al0[2], ah1[2], al1[2];
        {
            const int g0 = t * 8 + q, g1 = g0 + 4;
#pragma unroll
            for (int a = 0; a < 2; ++a) {
                const int ro = (arow + a * 16) * 8;
                ah0[a] = *(const bf16x8*)(Ahp + g0 * 4096 + ro);
                al0[a] = *(const bf16x8*)(Alp + g0 * 4096 + ro);
                ah1[a] = *(const bf16x8*)(Ahp + g1 * 4096 + ro);
                al1[a] = *(const bf16x8*)(Alp + g1 * 4096 + ro);
            }
        }
        // (2) W(t): fp32 regs -> hi/lo split -> swizzled LDS
        {
            bf16x8 h0, l0, h1, l1;
            cvt8(wcur[0], wcur[1], h0, l0);
            cvt8(wcur[2], wcur[3], h1, l1);
            *(bf16x8*)(BsH + so_a) = h0;
            *(bf16x8*)(BsL + so_a) = l0;
            *(bf16x8*)(BsH + so_b) = h1;
            *(bf16x8*)(BsL + so_b) = l1;
        }
        asm volatile("s_waitcnt lgkmcnt(0)" ::: "memory");
        __builtin_amdgcn_s_barrier();               // B(t) published; A-frag
                                                    // and W loads keep flying
        // (3) W reg-prefetch for t+1 (consumed at t+1's cvt)
        if (t < 15) {
            const int o = (t + 1) * 16;
#pragma unroll
            for (int j = 0; j < 4; ++j) wnxt[j] = wp[o + j];
        }
        // (4) compute: 2 x (8 ds_read_b128 B-frags -> 48 MFMA)
#pragma unroll
        for (int kk = 0; kk < 2; ++kk) {
            const int kg = kk * 4 + q;
            bf16x8 bh[4], bl[4];
#pragma unroll
            for (int b = 0; b < 4; ++b) {
                const int n = b * 16 + lrow;
                const int off = n * 64 + ((kg ^ (n & 7)) * 8);
                bh[b] = *(const bf16x8*)(BsH + off);
                bl[b] = *(const bf16x8*)(BsL + off);
            }
            __builtin_amdgcn_s_setprio(1);
#pragma unroll
            for (int a = 0; a < 2; ++a)
#pragma unroll
                for (int b = 0; b < 4; ++b) {
                    const bf16x8 Ah = kk ? ah1[a] : ah0[a];   // static (unrolled)
                    const bf16x8 Al = kk ? al1[a] : al0[a];
                    acc[a][b] = MFMA16(Ah, bh[b], acc[a][b]);
                    acc[a][b] = MFMA16(Ah, bl[b], acc[a][b]);
                    acc[a][b] = MFMA16(Al, bh[b], acc[a][b]);
                }
            __builtin_amdgcn_s_setprio(0);
        }
        asm volatile("s_waitcnt lgkmcnt(0)" ::: "memory");
        __builtin_amdgcn_s_barrier();               // B consumed -> reusable
        if (t < 15) {
#pragma unroll
            for (int j = 0; j < 4; ++j) wcur[j] = wnxt[j];
        }
    }

    // ---- epilogue: exp, rowsum atomics, P-hat^T store ----
    // wave wv owns m-rows [bm0+wv*32, +32), all 64 n-cols
#pragma unroll
    for (int a = 0; a < 2; ++a) {
        float rs[4] = {0.f, 0.f, 0.f, 0.f};
#pragma unroll
        for (int b = 0; b < 4; ++b) {
            const bool cok = (bn0 + b * 16 + lrow) < 50000;
#pragma unroll
            for (int r = 0; r < 4; ++r) {
                const float e = __expf(acc[a][b][r] - SHIFT);
                acc[a][b][r] = e;
                if (cok) rs[r] += e;
            }
        }
#pragma unroll
        for (int r = 0; r < 4; ++r) {
            float v = rs[r];
            v += __shfl_xor(v, 1, 16);
            v += __shfl_xor(v, 2, 16);
            v += __shfl_xor(v, 4, 16);
            v += __shfl_xor(v, 8, 16);
            const int row = bm0 + wv * 32 + a * 16 + q * 4 + r;
            if (lrow == 0 && row < 500) atomicAdd(Rsum + row, v);
        }
    }
    // per-wave transpose: Tt[v_loc 0..63][k_loc 0..31]; reuses sm (all B
    // reads retired at the loop's trailing barrier)
    bf16_t* Tt = sm + wv * (64 * TTS);              // 5120 B/wave
#pragma unroll
    for (int a = 0; a < 2; ++a)
#pragma unroll
        for (int b = 0; b < 4; ++b) {
            bf16x4 p;
#pragma unroll
            for (int r = 0; r < 4; ++r) p[r] = (bf16_t)acc[a][b][r];
            *(bf16x4*)(Tt + (b * 16 + lrow) * TTS + a * 16 + q * 4) = p;
        }
    // coalesced store: 4 lanes cover one v-row's 64B (32 k-elems)
    const long kbase = bm0 + wv * 32;
#pragma unroll
    for (int it = 0; it < 4; ++it) {
        const int u = it * 64 + lane;
        const int vl = u >> 2, ck = u & 3;
        bf16x8 d = *(const bf16x8*)(Tt + vl * TTS + ck * 8);
        *(bf16x8*)(Pt + (long)(bn0 + vl) * 512 + kbase + ck * 8) = d;
    }
}

// ---------------- K3: packed T2p[g][i][8] = theta/rowsum (else 0) ---------
__global__ void build_theta2(const float* __restrict__ theta,
                             const int* __restrict__ tidx,
                             const float* __restrict__ rsum,
                             bf16_t* __restrict__ T2p)
{
    const int i = blockIdx.x, rr = threadIdx.x;     // i batch, rr in [0,512)
    const int base = tidx[i] * 50;
    bf16_t v = (bf16_t)0.0f;
    if (rr >= base && rr < base + 50)
        v = (bf16_t)(theta[i * 50 + (rr - base)] / rsum[rr]);
    T2p[(rr >> 3) * 2048 + i * 8 + (rr & 7)] = v;
}

// ---------------- K4: stage full Pt-block once, barrier-free K-loop -------
__global__ __launch_bounds__(256, 4)
void gemm_out(const bf16_t* __restrict__ T2p, const bf16_t* __restrict__ Pt,
              float* __restrict__ out)
{
    // union: loop Bs = [64][512] bf16 swz (64KB); epilogue smo = [256][66] f32
    __shared__ __align__(16) char smraw[67584];
    bf16_t* Bs = (bf16_t*)smraw;
    float* smo = (float*)smraw;

    const int tid = threadIdx.x;
    const int wave = tid >> 6, lane = tid & 63;
    const int bn0 = blockIdx.x * 64;
    const int lrow = lane & 15, q = lane >> 4;

    // stage all of B (this block's 64 Pt rows x 512 k) in one GLDS burst.
    // LDS dest linear (wave-uniform base), source inverse-swizzled (rule 21).
#pragma unroll
    for (int rr = 0; rr < 16; ++rr) {
        const int ub = rr * 4096 + wave * 1024;     // uniform byte base
        const int off = ub + lane * 16;             // this lane's dest byte
        const int row = off >> 10;                  // 0..63
        const int c = (off >> 4) & 63;              // 16B chunk in row
        const int cs = c ^ (row & 7);
        GLDS(Pt + (long)(bn0 + row) * 512 + cs * 8, ((char*)Bs) + ub);
    }
    __syncthreads();

    f32x4 acc[4][4] = {};
#pragma unroll 4
    for (int kk = 0; kk < 16; ++kk) {
        const int g = kk * 4 + q;                   // k-chunk 0..63
        bf16x8 af[4];
#pragma unroll
        for (int a = 0; a < 4; ++a)
            af[a] = *(const bf16x8*)(T2p + g * 2048 +
                                     (wave * 64 + a * 16 + lrow) * 8);
#pragma unroll
        for (int b = 0; b < 4; ++b) {
            const int n = b * 16 + lrow;
            bf16x8 bfr = *(const bf16x8*)(Bs + n * 512 + ((g ^ (n & 7)) * 8));
#pragma unroll
            for (int a = 0; a < 4; ++a)
                acc[a][b] = MFMA16(af[a], bfr, acc[a][b]);
        }
    }
    __syncthreads();                                // Bs dead for ALL waves
    // acc -> LDS [256][66] f32 (pad 66 spreads banks across q-rows)
#pragma unroll
    for (int a = 0; a < 4; ++a)
#pragma unroll
        for (int b = 0; b < 4; ++b)
#pragma unroll
            for (int r = 0; r < 4; ++r)
                smo[(wave * 64 + a * 16 + q * 4 + r) * 66 + b * 16 + lrow] =
                    acc[a][b][r];
    __syncthreads();
    // coalesced out store: one instr = 4 rows x 256B contiguous segments
#pragma unroll
    for (int it = 0; it < 16; ++it) {
        const int row = it * 16 + (tid >> 4);       // 0..255
        const int col0 = (tid & 15) * 4;            // 0..60
        const float4 v = *(const float4*)(smo + row * 66 + col0);
        if (bn0 + col0 < 50000)
            *(float4*)(out + (long)row * 50000 + bn0 + col0) = v;
    }
}

extern "C" void kernel_launch(void* const* d_in, const int* in_sizes, int n_in,
                              void* d_out, int out_size, void* d_ws, size_t ws_size,
                              hipStream_t stream)
{
    const float* theta = (const float*)d_in[0];   // (256,50) fp32
    const float* wemb  = (const float*)d_in[1];   // (50000,1024) fp32
    const float* temb  = (const float*)d_in[2];   // (500,1024) fp32
    const int*   tidx  = (const int*)d_in[3];     // (256,)
    float* out = (float*)d_out;                   // (256,50000) fp32

    char* ws = (char*)d_ws;
    bf16_t* Pt   = (bf16_t*)ws;                   // 50048*512*2 = 51,249,152
    float*  rsum = (float*)(ws + 51249152);       // 2 KB
    bf16_t* Ahp  = (bf16_t*)(ws + 51251200);      // 1,048,576 (packed hi)
    bf16_t* Alp  = (bf16_t*)(ws + 52299776);      // 1,048,576 (packed lo)
    bf16_t* T2p  = (bf16_t*)(ws + 51251200);      // aliases Ahp (dead post-K1)

    prep_pack   <<<dim3(256),  256, 0, stream>>>(temb, Ahp, Alp, rsum);
    gemm_logits <<<dim3(3128), 256, 0, stream>>>(Ahp, Alp, wemb, Pt, rsum);
    build_theta2<<<dim3(256),  512, 0, stream>>>(theta, tidx, rsum, T2p);
    gemm_out    <<<dim3(782),  256, 0, stream>>>(T2p, Pt, out);
}